// Round 16
// baseline (35.466 us; speedup 1.0000x reference)
//
#include <hip/hip_runtime.h>
#include <math.h>

// Problem constants: V=50000, D=100, B=16, S=128, U=100, L=2
#define NB 16
#define SS 128
#define DD 100
#define KK 100
#define T_TILE 8            // output positions per block
#define P_HALO 11           // T_TILE + 3 (dependency cone)
#define NTILES 16           // SS / T_TILE
#define NT 768              // threads per block (12 waves, 3/SIMD)
#define NWAVES 12
#define CH_D4 5             // d4-rows per chunk
#define NCHUNK 5            // 25 d4-rows total (D=100)
#define XROWF 128           // global x-row stride (512B lines)

typedef float sf16 __attribute__((ext_vector_type(16)));
typedef float sf4  __attribute__((ext_vector_type(4)));

__device__ __forceinline__ float dot4(const float4 a, const float4 b) {
  return a.x * b.x + a.y * b.y + a.z * b.z + a.w * b.w;
}

// 20-float wave-uniform scalar load (16+4). Pointer MUST be wave-uniform
// (derive from readfirstlane'd wid) or clang can't allocate the SGPR pair.
__device__ __forceinline__ void sl20(const float* p, sf16& a, sf4& b) {
  asm volatile("s_load_dwordx16 %0, %2, 0x0\n\t"
               "s_load_dwordx4  %1, %2, 0x40"
               : "=s"(a), "=s"(b) : "s"((unsigned long long)p));
}

// ---------------------------------------------------------------------------
// Chunk staging (champion addresses). element e: part=e/500, r=(e%500)/100,
// k=e%100; source = gv_part + k*DD + 4*(c*CH_D4 + r).
// ---------------------------------------------------------------------------
__device__ __forceinline__ void ld_chunk(const float* __restrict__ gvr,
                                         const float* __restrict__ gvi,
                                         int c, int tid,
                                         float4& pv0, float4& pv1) {
  const int e0 = tid;
  const int p0 = e0 / 500, rm0 = e0 % 500, r0_ = rm0 / 100, k0_ = rm0 % 100;
  pv0 = *(const float4*)((p0 ? gvi : gvr) + k0_ * DD + 4 * (CH_D4 * c + r0_));
  const int e1 = tid + NT;
  if (e1 < 1000) {
    const int p1 = e1 / 500, rm1 = e1 % 500, r1_ = rm1 / 100, k1_ = rm1 % 100;
    pv1 = *(const float4*)((p1 ? gvi : gvr) + k1_ * DD + 4 * (CH_D4 * c + r1_));
  }
}
__device__ __forceinline__ void st_chunk(float4 (*__restrict__ vt)[1000],
                                         int buf, int tid,
                                         const float4& pv0, const float4& pv1) {
  vt[buf][tid] = pv0;
  if (tid + NT < 1000) vt[buf][tid + NT] = pv1;
}

// ---------------------------------------------------------------------------
// Stage-1 per-chunk accumulate (champion, complex x from LDS) + in-loop norm.
// ---------------------------------------------------------------------------
__device__ __forceinline__ void accum_pair0(
    const float4* __restrict__ vtb,
    const float4 (*__restrict__ bxr)[25], const float4 (*__restrict__ bxi)[25],
    int p0, int p1, bool a0, bool a1, int k, int c,
    float& r0a, float& i0a, float& r1a, float& i1a, float& n0)
{
#pragma unroll
  for (int r = 0; r < CH_D4; ++r) {
    const int d4 = c * CH_D4 + r;
    const float4 vr4 = vtb[r * KK + k];
    const float4 vi4 = vtb[500 + r * KK + k];
    n0 += dot4(vr4, vr4) + dot4(vi4, vi4);
    if (a0) {
      const float4 x4 = bxr[p0][d4];
      const float4 z4 = bxi[p0][d4];
      r0a += dot4(vr4, x4) + dot4(vi4, z4);
      i0a += dot4(vr4, z4) - dot4(vi4, x4);
    }
    if (a1) {
      const float4 x4 = bxr[p1][d4];
      const float4 z4 = bxi[p1][d4];
      r1a += dot4(vr4, x4) + dot4(vi4, z4);
      i1a += dot4(vr4, z4) - dot4(vi4, x4);
    }
  }
}

// ---------------------------------------------------------------------------
// Stage 1 (champion): complex x from LDS; m1 -> GLOBAL rows (512B stride).
// On exit pv holds gnr's chunk 0.
// ---------------------------------------------------------------------------
__device__ __forceinline__ void run_stage1(
    const float* __restrict__ gvr, const float* __restrict__ gvi,
    const float* __restrict__ gnr, const float* __restrict__ gni,
    float4 (*__restrict__ vt)[1000],
    const float4 (*__restrict__ bxr)[25], const float4 (*__restrict__ bxi)[25],
    float* __restrict__ m1g,
    const int tid, const int lane, const int wid,
    float4& pv0, float4& pv1)
{
  st_chunk(vt, 0, tid, pv0, pv1);
  __syncthreads();

  const int s0 = wid, s1 = wid + NWAVES;
  float a0r = 0.f, a0i = 0.f, a1r = 0.f, a1i = 0.f, n0 = 0.f;
  const int kk = (s0 & 1) * 50 + lane;
  const int pp0 = s0 >> 1, pp1 = s1 >> 1;
  const bool act0 = (s0 < 2 * P_HALO), act1 = (s1 < 2 * P_HALO);

  for (int c = 0; c < NCHUNK; ++c) {
    const int buf = c & 1;
    if (c + 1 < NCHUNK) ld_chunk(gvr, gvi, c + 1, tid, pv0, pv1);
    else                ld_chunk(gnr, gni, 0,     tid, pv0, pv1);
    if (lane < 50)
      accum_pair0(vt[buf], bxr, bxi, pp0, pp1, act0, act1, kk, c,
                  a0r, a0i, a1r, a1i, n0);
    if (c + 1 < NCHUNK) st_chunk(vt, buf ^ 1, tid, pv0, pv1);
    __syncthreads();
  }

  if (lane < 50) {
    const float rcp = 1.0f / n0;
    if (act0) m1g[pp0 * XROWF + kk] = (a0r * a0r + a0i * a0i) * rcp;
    if (act1) m1g[pp1 * XROWF + kk] = (a1r * a1r + a1i * a1i) * rcp;
  }
}

// ---------------------------------------------------------------------------
// Stages 2/3: real x via s_load from global rows (SGPRs, SMEM pipe — zero
// LDS x-traffic). x chunk issued one iteration ahead; one lgkm wait per chunk
// (right after the barrier, where LDS is quiet). V path = champion.
// Writes y2 raw + publishes invvn. Caller must __syncthreads() after return.
// ---------------------------------------------------------------------------
__device__ __forceinline__ void run_stage_sx(
    const float* __restrict__ gvr, const float* __restrict__ gvi,
    const float* __restrict__ gnr, const float* __restrict__ gni,
    const float* __restrict__ xrow0, const float* __restrict__ xrow1,
    float4 (*__restrict__ vt)[1000],
    float2* __restrict__ y2flat, float* __restrict__ invvn, const int nslots,
    const int tid, const int lane, const int wid,
    float4& pv0, float4& pv1)
{
  st_chunk(vt, 0, tid, pv0, pv1);
  sf16 xa0, xa1; sf4 xb0, xb1;
  sl20(xrow0, xa0, xb0);                    // x chunk 0, issued pre-barrier
  sl20(xrow1, xa1, xb1);
  __syncthreads();

  const int s0 = wid, s1 = wid + NWAVES;
  float a0r = 0.f, a0i = 0.f, a1r = 0.f, a1i = 0.f, n0 = 0.f;
  const int kk = (s0 & 1) * 50 + lane;
  const int pp0 = s0 >> 1, pp1 = s1 >> 1;
  const bool act0 = (s0 < nslots), act1 = (s1 < nslots);

  for (int c = 0; c < NCHUNK; ++c) {
    const int buf = c & 1;
    // x(c) ready after this wait (issued a full iteration ago; LDS quiet here)
    asm volatile("s_waitcnt lgkmcnt(0)"
                 : "+s"(xa0), "+s"(xb0), "+s"(xa1), "+s"(xb1));
    if (c + 1 < NCHUNK)  ld_chunk(gvr, gvi, c + 1, tid, pv0, pv1);
    else if (gnr)        ld_chunk(gnr, gni, 0,     tid, pv0, pv1);
    if (lane < 50) {
      const float4* vtb = vt[buf];
#pragma unroll
      for (int r = 0; r < CH_D4; ++r) {
        const float4 vr4 = vtb[r * KK + kk];
        const float4 vi4 = vtb[500 + r * KK + kk];
        n0 += dot4(vr4, vr4) + dot4(vi4, vi4);
        float x00, x01, x02, x03, x10, x11, x12, x13;
        if (r < 4) {
          x00 = xa0[4*r+0]; x01 = xa0[4*r+1]; x02 = xa0[4*r+2]; x03 = xa0[4*r+3];
          x10 = xa1[4*r+0]; x11 = xa1[4*r+1]; x12 = xa1[4*r+2]; x13 = xa1[4*r+3];
        } else {
          x00 = xb0[0]; x01 = xb0[1]; x02 = xb0[2]; x03 = xb0[3];
          x10 = xb1[0]; x11 = xb1[1]; x12 = xb1[2]; x13 = xb1[3];
        }
        if (act0) {
          a0r += vr4.x * x00 + vr4.y * x01 + vr4.z * x02 + vr4.w * x03;
          a0i += vi4.x * x00 + vi4.y * x01 + vi4.z * x02 + vi4.w * x03;
        }
        if (act1) {
          a1r += vr4.x * x10 + vr4.y * x11 + vr4.z * x12 + vr4.w * x13;
          a1i += vi4.x * x10 + vi4.y * x11 + vi4.z * x12 + vi4.w * x13;
        }
      }
    }
    if (c + 1 < NCHUNK) {                       // issue x(c+1) after consume
      sl20(xrow0 + 20 * (c + 1), xa0, xb0);
      sl20(xrow1 + 20 * (c + 1), xa1, xb1);
      st_chunk(vt, buf ^ 1, tid, pv0, pv1);
    }
    __syncthreads();
  }

  if (lane < 50) {
    const float rcp = 1.0f / n0;
    if (act0) y2flat[pp0 * KK + kk] = make_float2(a0r, a0i);
    if (act1) y2flat[pp1 * KK + kk] = make_float2(a1r, a1i);
    if (wid < 2) invvn[kk] = rcp;   // waves 0,1 cover k=0..49 / 50..99
  }
}

// ---------------------------------------------------------------------------
__global__ __launch_bounds__(NT) void k_fused(
    const int* __restrict__ seq,
    const float* __restrict__ ampT, const float* __restrict__ phT,
    const float* __restrict__ pkr, const float* __restrict__ pki,
    const float* __restrict__ mkr, const float* __restrict__ mki,
    float* __restrict__ M1, float* __restrict__ M2, float* __restrict__ part)
{
  __shared__ float4 vt[2][1000];        // 32000 B: V chunk double-buffer
  __shared__ float4 xr4[P_HALO][25];    // stage-1 phi real
  __shared__ float4 xi4[P_HALO][25];    // stage-1 phi imag
  __shared__ float4 m4[P_HALO][25];     // epilogue scratch
  __shared__ float2 y2[P_HALO][KK];     // projection pair outputs
  __shared__ float es[SS];
  __shared__ float wnl[SS];
  __shared__ float invvn[KK];
  __shared__ float redw[NWAVES];
  __shared__ float sc[3];               // E, Z1, Z2

  const int tid  = threadIdx.x;
  const int lane = tid & 63;
  // wave id MUST be wave-uniform-provable for s_load pointer math (R15 fix)
  const int wid  = __builtin_amdgcn_readfirstlane(tid >> 6);
  const int bt   = blockIdx.x;
  const int b    = bt >> 4;
  const int tile = bt & 15;
  const int t0   = tile * T_TILE;
  const int sb   = b * SS;

  float* m1g = M1 + bt * (P_HALO * XROWF);      // [11][128]
  float* m2g = M2 + bt * (10 * XROWF);          // [10][128]

  // stage-1 chunk 0: issued FIRST, hidden under the whole prologue
  float4 pv0, pv1;
  ld_chunk(pkr, pki, 0, tid, pv0, pv1);

  // --- prologue A: norms + exp for ALL 128 positions of this batch ---
  if (tid < 4 * SS) {
    const int t = tid >> 2, q = tid & 3;
    const int row = seq[sb + t];
    const float* ap = ampT + (long)row * DD + q;
    float s = 0.f;
#pragma unroll
    for (int i = 0; i < 25; ++i) { const float a = ap[4*i]; s += a * a; }
    s += __shfl_xor(s, 1, 64);
    s += __shfl_xor(s, 2, 64);
    if (q == 0) { const float nrm = sqrtf(s); wnl[t] = nrm; es[t] = expf(nrm); }
  }
  __syncthreads();

  // --- E and closed-form softmax denominators ---
  {
    float v = (tid < SS) ? es[tid] : 0.f;
    for (int m = 32; m; m >>= 1) v += __shfl_xor(v, m, 64);
    if (lane == 0) redw[wid] = v;
  }
  // --- prologue B: phi = (amp/||amp||) * e^{i phase} for halo positions ---
  for (int idx = tid; idx < P_HALO * 25; idx += NT) {
    const int p = idx / 25, d4 = idx % 25;
    const int tp = t0 + p;
    float4 o_r = {0.f, 0.f, 0.f, 0.f}, o_i = {0.f, 0.f, 0.f, 0.f};
    if (tp < SS) {
      const int row = seq[sb + tp];
      const float4 a4 = *(const float4*)(ampT + (long)row * DD + 4 * d4);
      const float4 p4 = *(const float4*)(phT  + (long)row * DD + 4 * d4);
      const float inv = 1.0f / wnl[tp];
      float sv, cv;
      sincosf(p4.x, &sv, &cv); o_r.x = a4.x * inv * cv; o_i.x = a4.x * inv * sv;
      sincosf(p4.y, &sv, &cv); o_r.y = a4.y * inv * cv; o_i.y = a4.y * inv * sv;
      sincosf(p4.z, &sv, &cv); o_r.z = a4.z * inv * cv; o_i.z = a4.z * inv * sv;
      sincosf(p4.w, &sv, &cv); o_r.w = a4.w * inv * cv; o_i.w = a4.w * inv * sv;
    }
    xr4[p][d4] = o_r;
    xi4[p][d4] = o_i;
  }
  __syncthreads();
  if (tid == 0) {
    float E = 0.f;
    for (int w = 0; w < NWAVES; ++w) E += redw[w];
    sc[0] = E;
    sc[1] = E - es[0] + 1.0f;
    sc[2] = E - es[0] - es[1] + 2.0f;
  }
  __syncthreads();

  // --- stage 1: m1[p][k] -> global rows (visible after next barrier) ---
  run_stage1(pkr, pki, pkr + DD * DD, pki + DD * DD, vt, xr4, xi4,
             m1g, tid, lane, wid, pv0, pv1);
  __syncthreads();    // vmcnt drained -> m1 rows visible to s_load

  // --- stage 2: y2 = <v1, m1> with x from SGPRs ---
  {
    const int pp0 = wid >> 1, pp1 = (wid + NWAVES) >> 1;
    const float* xr0 = m1g + min(pp0, P_HALO - 1) * XROWF;
    const float* xr1 = m1g + min(pp1, P_HALO - 1) * XROWF;
    run_stage_sx(pkr + DD * DD, pki + DD * DD, mkr, mki, xr0, xr1, vt,
                 (float2*)y2, invvn, 2 * P_HALO, tid, lane, wid, pv0, pv1);
  }
  __syncthreads();

  // --- m2 = 2-tap window of y2, squared, * invvn -> global rows ---
  {
    const float E = sc[0], Z1 = sc[1];
    for (int idx = tid; idx < 10 * KK; idx += NT) {
      const int p = idx / KK, k = idx - p * KK;
      const int t = t0 + p;
      const float w0 = ((t     < SS) ? es[t]     : 1.f) / E;
      const float w1 = ((t + 1 < SS) ? es[t + 1] : 1.f) / Z1;
      const float2 ya = y2[p][k], yb = y2[p + 1][k];
      const float ar = w0 * ya.x + w1 * yb.x;
      const float ai = w0 * ya.y + w1 * yb.y;
      m2g[p * XROWF + k] = (ar * ar + ai * ai) * invvn[k];
    }
  }
  __syncthreads();    // m2 rows visible to s_load

  // --- stage 3: y2 = <u, m2> with x from SGPRs ---
  {
    const int pp0 = wid >> 1, pp1 = (wid + NWAVES) >> 1;
    const float* xr0 = m2g + min(pp0, 9) * XROWF;
    const float* xr1 = m2g + min(pp1, 9) * XROWF;
    run_stage_sx(mkr, mki, nullptr, nullptr, xr0, xr1, vt,
                 (float2*)y2, invvn, 20, tid, lane, wid, pv0, pv1);
  }
  __syncthreads();

  // --- final: 3-tap window, square, * wn[t] * invvn_U[k]; sum over own p ---
  {
    const float E = sc[0], Z1 = sc[1], Z2 = sc[2];
    for (int idx = tid; idx < T_TILE * KK; idx += NT) {
      const int p = idx / KK, k = idx - p * KK;
      const int t = t0 + p;                         // < 128 always
      const float w0 = es[t] / E;
      const float w1 = ((t + 1 < SS) ? es[t + 1] : 1.f) / Z1;
      const float w2 = ((t + 2 < SS) ? es[t + 2] : 1.f) / Z2;
      const float2 ya = y2[p][k], yb = y2[p + 1][k], yc = y2[p + 2][k];
      const float qr = w0 * ya.x + w1 * yb.x + w2 * yc.x;
      const float qi = w0 * ya.y + w1 * yb.y + w2 * yc.y;
      ((float*)m4)[p * KK + k] = wnl[t] * (qr * qr + qi * qi) * invvn[k];
    }
  }
  __syncthreads();
  if (tid < KK) {
    float s = 0.f;
#pragma unroll
    for (int p = 0; p < T_TILE; ++p) s += ((float*)m4)[p * KK + tid];
    part[bt * KK + tid] = s;
  }
}

// ---------------------------------------------------------------------------
// Output: probs[b,k] = sum_tiles part; out = probs @ dense_w + dense_b
// ---------------------------------------------------------------------------
__global__ __launch_bounds__(128) void k_out(
    const float* __restrict__ part, const float* __restrict__ dw,
    const float* __restrict__ db, float* __restrict__ out)
{
  __shared__ float pr[KK];
  const int b = blockIdx.x, tid = threadIdx.x;
  if (tid < KK) {
    float s = 0.f;
#pragma unroll
    for (int q = 0; q < NTILES; ++q) s += part[(b * NTILES + q) * KK + tid];
    pr[tid] = s;
  }
  __syncthreads();
  if (tid < 2) {
    float s = db[tid];
    for (int k = 0; k < KK; ++k) s += pr[k] * dw[k * 2 + tid];
    out[b * 2 + tid] = s;
  }
}

// ---------------------------------------------------------------------------
extern "C" void kernel_launch(void* const* d_in, const int* in_sizes, int n_in,
                              void* d_out, int out_size, void* d_ws, size_t ws_size,
                              hipStream_t stream) {
  const int*   seq  = (const int*)d_in[0];
  const float* ampT = (const float*)d_in[1];
  const float* phT  = (const float*)d_in[2];
  const float* pkr  = (const float*)d_in[3];
  const float* pki  = (const float*)d_in[4];
  const float* mkr  = (const float*)d_in[5];
  const float* mki  = (const float*)d_in[6];
  const float* dw   = (const float*)d_in[7];
  const float* db   = (const float*)d_in[8];
  float* out = (float*)d_out;

  float* ws   = (float*)d_ws;
  float* part = ws;                                   // [256][100]
  float* M1   = ws + 25600;                           // [256][11][128]
  float* M2   = M1 + 256 * P_HALO * XROWF;            // [256][10][128]
  // total ws: ~2.85 MB

  k_fused<<<NB * NTILES, NT, 0, stream>>>(seq, ampT, phT, pkr, pki, mkr, mki,
                                          M1, M2, part);
  k_out  <<<NB,          128, 0, stream>>>(part, dw, db, out);
}